// Round 3
// baseline (2166.892 us; speedup 1.0000x reference)
//
#include <hip/hip_runtime.h>
#include <math.h>

typedef float v4 __attribute__((ext_vector_type(4)));

#define NN 100000   // nodes
#define NE 100000   // events
#define MD 128      // MEM_D
#define RD 64       // RAW_D
#define TD 64       // TIME_D
#define GD 384      // 3*MEM_D (gate dim)
#define MSGD 512    // MSG_D
#define BE 64       // events per block (k_event)
#define BN 64       // nodes per block (k_node)

// ---------------------------------------------------------------------------
// Kernel 1: per-event fused gather + (msg @ W_ih^T) + scatter-add into gsum.
// gsum[n] accumulates msg_e @ W_ih^T for every event e touching node n
// (n in {src,dst,prod}); by linearity gi = gsum/count + b_ih.
// ---------------------------------------------------------------------------
__global__ __launch_bounds__(256)
void k_event(const int* __restrict__ src, const int* __restrict__ dst,
             const int* __restrict__ prod, const int* __restrict__ t,
             const float* __restrict__ raw, const float* __restrict__ mem,
             const int* __restrict__ lu,
             const float* __restrict__ W_t, const float* __restrict__ b_t,
             const float* __restrict__ W_ih,
             float* __restrict__ gsum, int* __restrict__ cnt,
             int* __restrict__ tmax)
{
  __shared__ float msg[BE][MD];     // one 128-wide k-chunk of the msg tile
  __shared__ int s_s[BE], s_d[BE], s_p[BE];
  __shared__ float s_tr[BE];
  const int tid = threadIdx.x;
  const int e0 = blockIdx.x * BE;

  if (tid < BE) {
    int e = min(e0 + tid, NE - 1);
    int s = src[e];
    s_s[tid] = s;
    s_d[tid] = dst[e];
    s_p[tid] = prod[e];
    s_tr[tid] = (float)(t[e] - lu[s]);
  }

  const int tc = tid & 31;   // column group: cols c = j*32 + tc
  const int te = tid >> 5;   // event group: events te*8 .. te*8+7

  float acc[8][12];
  #pragma unroll
  for (int i = 0; i < 8; ++i)
    #pragma unroll
    for (int j = 0; j < 12; ++j) acc[i][j] = 0.f;

  // 4 k-chunks of 128: mem[src], mem[dst], mem[prod], [raw|t_enc]
  for (int ch = 0; ch < 4; ++ch) {
    __syncthreads();
    if (ch < 3) {
      const int* ia = (ch == 0) ? s_s : (ch == 1) ? s_d : s_p;
      #pragma unroll
      for (int it = 0; it < 8; ++it) {
        int idx = tid + it * 256;      // 2048 vec4 slots = 64 rows x 32
        int e = idx >> 5, q = idx & 31;
        int row = ia[e];
        v4 v = *reinterpret_cast<const v4*>(mem + (size_t)row * MD + q * 4);
        *reinterpret_cast<v4*>(&msg[e][q * 4]) = v;
      }
    } else {
      #pragma unroll
      for (int it = 0; it < 8; ++it) {
        int idx = tid + it * 256;
        int e = idx >> 5, q = idx & 31;
        if (q < 16) {
          int ev = min(e0 + e, NE - 1);
          v4 v = *reinterpret_cast<const v4*>(raw + (size_t)ev * RD + q * 4);
          *reinterpret_cast<v4*>(&msg[e][q * 4]) = v;
        } else {
          int j0 = (q - 16) * 4;
          float tr = s_tr[e];
          v4 v;
          v.x = cosf(tr * W_t[j0 + 0] + b_t[j0 + 0]);
          v.y = cosf(tr * W_t[j0 + 1] + b_t[j0 + 1]);
          v.z = cosf(tr * W_t[j0 + 2] + b_t[j0 + 2]);
          v.w = cosf(tr * W_t[j0 + 3] + b_t[j0 + 3]);
          *reinterpret_cast<v4*>(&msg[e][q * 4]) = v;
        }
      }
    }
    __syncthreads();
    const float* Wc = W_ih + ch * MD;  // row stride MSGD, k-offset ch*128
    for (int k4 = 0; k4 < 32; ++k4) {
      v4 a[8];
      #pragma unroll
      for (int i = 0; i < 8; ++i)
        a[i] = *reinterpret_cast<const v4*>(&msg[te * 8 + i][k4 * 4]);
      #pragma unroll
      for (int j = 0; j < 12; ++j) {
        int c = j * 32 + tc;
        v4 w = *reinterpret_cast<const v4*>(Wc + (size_t)c * MSGD + k4 * 4);
        #pragma unroll
        for (int i = 0; i < 8; ++i)
          acc[i][j] += a[i].x * w.x + a[i].y * w.y + a[i].z * w.z + a[i].w * w.w;
      }
    }
  }

  // scatter y_e into the 3 destination nodes
  #pragma unroll
  for (int i = 0; i < 8; ++i) {
    int e = te * 8 + i;
    if (e0 + e < NE) {
      size_t bs = (size_t)s_s[e] * GD;
      size_t bd = (size_t)s_d[e] * GD;
      size_t bp = (size_t)s_p[e] * GD;
      #pragma unroll
      for (int j = 0; j < 12; ++j) {
        int c = j * 32 + tc;
        float v = acc[i][j];
        atomicAdd(&gsum[bs + c], v);
        atomicAdd(&gsum[bd + c], v);
        atomicAdd(&gsum[bp + c], v);
      }
    }
  }
  // counts + segment_max(t)
  if (tid < BE) {
    int e = e0 + tid;
    if (e < NE) {
      int tt = t[e];
      atomicAdd(&cnt[s_s[tid]], 1);
      atomicAdd(&cnt[s_d[tid]], 1);
      atomicAdd(&cnt[s_p[tid]], 1);
      atomicMax(&tmax[s_s[tid]], tt);
      atomicMax(&tmax[s_d[tid]], tt);
      atomicMax(&tmax[s_p[tid]], tt);
    }
  }
}

// ---------------------------------------------------------------------------
// Kernel 2: per-node gh = h @ W_hh^T, fused GRU cell, outputs + loss partial.
// ---------------------------------------------------------------------------
__global__ __launch_bounds__(256)
void k_node(const float* __restrict__ mem, const int* __restrict__ lu,
            const float* __restrict__ init_mem,
            const float* __restrict__ W_hh, const float* __restrict__ b_ih,
            const float* __restrict__ b_hh,
            const float* __restrict__ gsum, const int* __restrict__ cnt,
            const int* __restrict__ tmax,
            float* __restrict__ out_mem, float* __restrict__ out_lu,
            float* __restrict__ loss_acc)
{
  __shared__ float hs[BN][MD];
  __shared__ int s_c[BN];
  const int tid = threadIdx.x;
  const int n0 = blockIdx.x * BN;

  #pragma unroll
  for (int it = 0; it < 8; ++it) {
    int idx = tid + it * 256;
    int n = idx >> 5, q = idx & 31;
    int node = min(n0 + n, NN - 1);
    const float* sp = (lu[node] == -1) ? init_mem : mem;
    v4 v = *reinterpret_cast<const v4*>(sp + (size_t)node * MD + q * 4);
    *reinterpret_cast<v4*>(&hs[n][q * 4]) = v;
  }
  if (tid < BN) s_c[tid] = cnt[min(n0 + tid, NN - 1)];
  __syncthreads();

  const int tc = tid & 31, te = tid >> 5;
  const int d0 = tc * 4;
  float ar[8][4], az[8][4], an[8][4];
  #pragma unroll
  for (int i = 0; i < 8; ++i)
    #pragma unroll
    for (int j = 0; j < 4; ++j) { ar[i][j] = 0.f; az[i][j] = 0.f; an[i][j] = 0.f; }

  for (int k4 = 0; k4 < 32; ++k4) {
    v4 a[8];
    #pragma unroll
    for (int i = 0; i < 8; ++i)
      a[i] = *reinterpret_cast<const v4*>(&hs[te * 8 + i][k4 * 4]);
    #pragma unroll
    for (int j = 0; j < 4; ++j) {
      int d = d0 + j;
      v4 wr = *reinterpret_cast<const v4*>(W_hh + (size_t)d * MD + k4 * 4);
      v4 wz = *reinterpret_cast<const v4*>(W_hh + (size_t)(128 + d) * MD + k4 * 4);
      v4 wn = *reinterpret_cast<const v4*>(W_hh + (size_t)(256 + d) * MD + k4 * 4);
      #pragma unroll
      for (int i = 0; i < 8; ++i) {
        ar[i][j] += a[i].x * wr.x + a[i].y * wr.y + a[i].z * wr.z + a[i].w * wr.w;
        az[i][j] += a[i].x * wz.x + a[i].y * wz.y + a[i].z * wz.z + a[i].w * wz.w;
        an[i][j] += a[i].x * wn.x + a[i].y * wn.y + a[i].z * wn.z + a[i].w * wn.w;
      }
    }
  }

  float ss = 0.f;
  #pragma unroll
  for (int i = 0; i < 8; ++i) {
    int n = te * 8 + i;
    int node = n0 + n;
    if (node < NN) {
      int c = s_c[n];
      bool has = c > 0;
      float inv = 1.0f / (float)(c > 0 ? c : 1);
      const float* gs = gsum + (size_t)node * GD;
      v4 gr  = *reinterpret_cast<const v4*>(gs + d0);
      v4 gz  = *reinterpret_cast<const v4*>(gs + 128 + d0);
      v4 gn  = *reinterpret_cast<const v4*>(gs + 256 + d0);
      v4 bir = *reinterpret_cast<const v4*>(b_ih + d0);
      v4 biz = *reinterpret_cast<const v4*>(b_ih + 128 + d0);
      v4 bin_ = *reinterpret_cast<const v4*>(b_ih + 256 + d0);
      v4 bhr = *reinterpret_cast<const v4*>(b_hh + d0);
      v4 bhz = *reinterpret_cast<const v4*>(b_hh + 128 + d0);
      v4 bhn = *reinterpret_cast<const v4*>(b_hh + 256 + d0);
      v4 hold = *reinterpret_cast<const v4*>(&hs[n][d0]);
      v4 o;
      #pragma unroll
      for (int j = 0; j < 4; ++j) {
        float i_r = gr[j] * inv + bir[j];
        float i_z = gz[j] * inv + biz[j];
        float i_n = gn[j] * inv + bin_[j];
        float h_r = ar[i][j] + bhr[j];
        float h_z = az[i][j] + bhz[j];
        float h_n = an[i][j] + bhn[j];
        float r = 1.f / (1.f + expf(-(i_r + h_r)));
        float z = 1.f / (1.f + expf(-(i_z + h_z)));
        float nn_ = tanhf(i_n + r * h_n);
        float nh = (1.f - z) * nn_ + z * hold[j];
        float ov = has ? nh : hold[j];
        o[j] = ov;
        float df = has ? (nh - hold[j]) : 0.f;
        ss += df * df;
      }
      *reinterpret_cast<v4*>(out_mem + (size_t)node * MD + d0) = o;
    }
  }

  // block-reduce squared-diff partial into global accumulator
  #pragma unroll
  for (int off = 32; off > 0; off >>= 1)
    ss += __shfl_down(ss, off);
  if ((tid & 63) == 0) atomicAdd(loss_acc, ss);

  if (tid < BN) {
    int node = n0 + tid;
    if (node < NN) {
      int c = s_c[tid];
      out_lu[node] = (float)(c > 0 ? tmax[node] : lu[node]);
    }
  }
}

__global__ void k_fin(const float* __restrict__ loss_acc, float* __restrict__ out_loss)
{
  out_loss[0] = sqrtf(loss_acc[0]) * (1.0f / (float)NN);
}

// ---------------------------------------------------------------------------
extern "C" void kernel_launch(void* const* d_in, const int* in_sizes, int n_in,
                              void* d_out, int out_size, void* d_ws, size_t ws_size,
                              hipStream_t stream)
{
  const int*   src      = (const int*)d_in[0];
  const int*   dst      = (const int*)d_in[1];
  const int*   prod     = (const int*)d_in[2];
  const int*   t        = (const int*)d_in[3];
  const float* raw      = (const float*)d_in[4];
  const float* mem      = (const float*)d_in[5];
  const int*   lu       = (const int*)d_in[6];
  const float* init_mem = (const float*)d_in[7];
  const float* W_t      = (const float*)d_in[8];
  const float* b_t      = (const float*)d_in[9];
  const float* W_ih     = (const float*)d_in[10];
  const float* W_hh     = (const float*)d_in[11];
  const float* b_ih     = (const float*)d_in[12];
  const float* b_hh     = (const float*)d_in[13];

  float* gsum = (float*)d_ws;
  size_t gsum_elems = (size_t)NN * GD;                 // 38.4M floats = 153.6 MB
  int* cnt  = (int*)(gsum + gsum_elems);
  int* tmax = cnt + NN;
  float* loss_acc = (float*)(tmax + NN);
  size_t init_bytes = (gsum_elems + 2 * (size_t)NN + 1) * 4;
  hipMemsetAsync(d_ws, 0, init_bytes, stream);          // t >= 0 so tmax=0 init is safe

  float* out_mem  = (float*)d_out;
  float* out_lu   = out_mem + (size_t)NN * MD;          // 12,800,000
  float* out_loss = out_lu + NN;                        // 12,900,000

  k_event<<<(NE + BE - 1) / BE, 256, 0, stream>>>(
      src, dst, prod, t, raw, mem, lu, W_t, b_t, W_ih, gsum, cnt, tmax);
  k_node<<<(NN + BN - 1) / BN, 256, 0, stream>>>(
      mem, lu, init_mem, W_hh, b_ih, b_hh, gsum, cnt, tmax,
      out_mem, out_lu, loss_acc);
  k_fin<<<1, 1, 0, stream>>>(loss_acc, out_loss);
}